// Round 7
// baseline (300.144 us; speedup 1.0000x reference)
//
#include <hip/hip_runtime.h>

#define CAP 48

typedef short  s8v  __attribute__((ext_vector_type(8)));
typedef float  f4v  __attribute__((ext_vector_type(4)));
typedef float  f2v  __attribute__((ext_vector_type(2)));

__device__ __forceinline__ unsigned short f2bf(float f) {
    unsigned u = __float_as_uint(f);
    u += 0x7FFFu + ((u >> 16) & 1u);      // RNE
    return (unsigned short)(u >> 16);
}
__device__ __forceinline__ float bflo(unsigned v) { return __uint_as_float(v << 16); }
__device__ __forceinline__ float bfhi(unsigned v) { return __uint_as_float(v & 0xffff0000u); }

// packed accumulate: 4 x v_pk_add_f32 instead of 8 x v_add_f32 per uint4
#define ACCP(v) do { \
    a0 += (f2v){bflo((v).x), bfhi((v).x)}; \
    a1 += (f2v){bflo((v).y), bfhi((v).y)}; \
    a2 += (f2v){bflo((v).z), bfhi((v).z)}; \
    a3 += (f2v){bflo((v).w), bfhi((v).w)}; } while(0)

// ---- merged prep: bucket CSR + x->bf16 convert + weight pack + BN fold -----
// blocks [0, nbBucket)               : edge bucketing
// blocks [nbBucket, nbBucket+nbCvt)  : fp32 -> bf16 convert of x
// blocks [nbBucket+nbCvt, +448)      : weight prepack (64 x 7 grid linearized)
__global__ __launch_bounds__(256) void k_prep(const int* __restrict__ src, const int* __restrict__ dst, int E,
                                              int* __restrict__ cnt, int* __restrict__ bucket,
                                              const float* __restrict__ x, unsigned short* __restrict__ xb, int n4,
                                              const float* W0, const float* W1, const float* W2,
                                              const float* W3, const float* W4, const float* W5,
                                              unsigned short* P0, unsigned short* P1, unsigned short* P2,
                                              unsigned short* P3, unsigned short* P4, unsigned short* P5,
                                              const float* g1, const float* be1, const float* rm1, const float* rv1, const float* bl1,
                                              const float* g2, const float* be2, const float* rm2, const float* rv2, const float* bl2,
                                              float* P,
                                              unsigned short* hb, unsigned short* hb2, unsigned short* t3b, int N,
                                              int nbBucket, int nbCvt) {
    int b = blockIdx.x;
    const int tid = threadIdx.x;
    if (b < nbBucket) {
        int e = b * 256 + tid;
        if (e < E) {
            int d = dst[e];
            int slot = atomicAdd(&cnt[d], 1);
            if (slot < CAP) bucket[(size_t)d * CAP + slot] = src[e];
        }
        return;
    }
    b -= nbBucket;
    if (b < nbCvt) {
        int i = b * 256 + tid;
        if (i < n4) {
            float4 v = ((const float4*)x)[i];
            ushort4 o;
            o.x = f2bf(v.x); o.y = f2bf(v.y); o.z = f2bf(v.z); o.w = f2bf(v.w);
            ((ushort4*)xb)[i] = o;
        }
        return;
    }
    b -= nbCvt;
    const int px = b & 63;
    const int py = b >> 6;
    if (py == 6) {
        if (px == 0 && tid < 128) {
            int i = tid;
            float s1 = g1[i] * rsqrtf(rv1[i] + 1e-5f);
            P[i]       = s1;
            P[128 + i] = (bl1[i] - rm1[i]) * s1 + be1[i];
            float s2 = g2[i] * rsqrtf(rv2[i] + 1e-5f);
            P[256 + i] = s2;
            P[384 + i] = (bl2[i] - rm2[i]) * s2 + be2[i];
            // zero row N of each feature buffer (gather padding target)
            xb [(size_t)N * 128 + i] = 0;
            hb [(size_t)N * 128 + i] = 0;
            hb2[(size_t)N * 128 + i] = 0;
            if (i < 64) t3b[(size_t)N * 64 + i] = 0;
        }
        return;
    }
    const float* W; unsigned short* Pk; int JD;
    switch (py) {
        case 0: W = W0; Pk = P0; JD = 128; break;
        case 1: W = W1; Pk = P1; JD = 128; break;
        case 2: W = W2; Pk = P2; JD = 128; break;
        case 3: W = W3; Pk = P3; JD = 128; break;
        case 4: W = W4; Pk = P4; JD = 64;  break;
        default:W = W5; Pk = P5; JD = 64;  break;
    }
    int o = px * 256 + tid;
    if (o >= 128 * JD) return;
    int j    = o & 7;
    int lane = (o >> 3) & 63;
    int t    = o >> 9;
    int nt   = t % (JD / 16);
    int kt   = t / (JD / 16);
    int k = kt * 32 + (lane >> 4) * 8 + j;
    int nn = nt * 16 + (lane & 15);
    Pk[o] = f2bf(W[(size_t)k * JD + nn]);
}

// ---- fused SAGE layer: gather-mean -> LDS, dual MFMA, BN+ReLU epilogue -----
// block = 32 nodes, 4 waves. Gather: quarter-wave per node (16 lanes x uint4),
// 2 serial slots/wave, branch-free unroll-8 rounds via zero-row clamping.
// Packed-f32 accumulation (v_pk_add_f32). VGPR guarded <= 64 (no cliff).
template<bool T3>
__global__ __launch_bounds__(256, 8) void k_fused(const unsigned short* __restrict__ feat,
                                               const int* __restrict__ cnt, const int* __restrict__ bucket,
                                               const unsigned short* __restrict__ Bl, const unsigned short* __restrict__ Br,
                                               const float* __restrict__ scale, const float* __restrict__ shift,
                                               unsigned short* __restrict__ out,
                                               const unsigned short* __restrict__ W3p, unsigned short* __restrict__ t3,
                                               int n) {
    __shared__ unsigned short sA[32 * 136];
    __shared__ unsigned short sH[T3 ? 32 * 136 : 8];
    const int tid  = threadIdx.x;
    const int wave = tid >> 6;
    const int lane = tid & 63;
    const int nb0  = blockIdx.x * 32;
    if (nb0 >= n) return;

    // ---- phase 1: gather-mean ----------------------------------------------
    {
        const int q4   = lane >> 4;
        const int li   = lane & 15;
        const int base = q4 << 4;
        const uint4* inp = (const uint4*)feat;     // 256B row = 16 x uint4
        int rows[2], cs[2], idxs[2];
        #pragma unroll
        for (int t = 0; t < 2; t++) {
            rows[t] = wave * 8 + t * 4 + q4;
            int node = nb0 + rows[t];
            bool ok = node < n;
            int c = ok ? cnt[node] : 0; if (c > CAP) c = CAP;
            cs[t] = c;
            idxs[t] = (ok && li < c) ? bucket[(size_t)node * CAP + li] : n;  // n = zero row
        }
        #pragma unroll
        for (int t = 0; t < 2; t++) {
            const int c = cs[t];
            f2v a0 = {0.f, 0.f}, a1 = {0.f, 0.f}, a2 = {0.f, 0.f}, a3 = {0.f, 0.f};
            if (c > 0) {
                #pragma unroll
                for (int u = 0; u < 8; u++) {
                    int idx = __shfl(idxs[t], base + u);        // >=c lanes hold n (zero row)
                    uint4 v = inp[(size_t)idx * 16 + li];
                    ACCP(v);
                }
            }
            if (c > 8) {
                #pragma unroll
                for (int u = 8; u < 16; u++) {
                    int idx = __shfl(idxs[t], base + u);
                    uint4 v = inp[(size_t)idx * 16 + li];
                    ACCP(v);
                }
            }
            const int node = nb0 + rows[t];
            for (int s = 16; s < c; s++) {                      // deg>16 (rare)
                int idx = bucket[(size_t)node * CAP + s];
                uint4 v = inp[(size_t)idx * 16 + li];
                ACCP(v);
            }
            if (node < n) {
                float iv = 1.0f / fmaxf((float)c, 1.0f);
                uint4 o;
                o.x = (unsigned)f2bf(a0[0] * iv) | ((unsigned)f2bf(a0[1] * iv) << 16);
                o.y = (unsigned)f2bf(a1[0] * iv) | ((unsigned)f2bf(a1[1] * iv) << 16);
                o.z = (unsigned)f2bf(a2[0] * iv) | ((unsigned)f2bf(a2[1] * iv) << 16);
                o.w = (unsigned)f2bf(a3[0] * iv) | ((unsigned)f2bf(a3[1] * iv) << 16);
                *(uint4*)(sA + rows[t] * 136 + li * 8) = o;
            }
        }
    }
    __syncthreads();

    // ---- phase 2: dual MFMA, wave = 32 rows x 32 cols (nt0 = wave*2) --------
    const int m = lane & 15;
    const int q = lane >> 4;
    const int nt0 = wave * 2;
    const int rg0 = min(nb0 + m,      n - 1);
    const int rg1 = min(nb0 + 16 + m, n - 1);

    f4v acc[2][2];
    #pragma unroll
    for (int mt = 0; mt < 2; mt++)
        #pragma unroll
        for (int c = 0; c < 2; c++) {
            acc[mt][c][0] = 0.f; acc[mt][c][1] = 0.f; acc[mt][c][2] = 0.f; acc[mt][c][3] = 0.f;
        }

    #pragma unroll
    for (int kt = 0; kt < 4; kt++) {
        const int ko = kt * 32 + q * 8;
        s8v a0 = *(const s8v*)(sA + m * 136 + ko);                // agg side (LDS)
        s8v a1 = *(const s8v*)(sA + (16 + m) * 136 + ko);
        s8v a0d = *(const s8v*)(feat + (size_t)rg0 * 128 + ko);   // root side (global)
        s8v a1d = *(const s8v*)(feat + (size_t)rg1 * 128 + ko);
        #pragma unroll
        for (int c = 0; c < 2; c++) {
            s8v b  = *(const s8v*)(Bl + ((size_t)(kt * 8 + nt0 + c) * 64 + lane) * 8);
            acc[0][c] = __builtin_amdgcn_mfma_f32_16x16x32_bf16(a0, b, acc[0][c], 0, 0, 0);
            acc[1][c] = __builtin_amdgcn_mfma_f32_16x16x32_bf16(a1, b, acc[1][c], 0, 0, 0);
            s8v b2 = *(const s8v*)(Br + ((size_t)(kt * 8 + nt0 + c) * 64 + lane) * 8);
            acc[0][c] = __builtin_amdgcn_mfma_f32_16x16x32_bf16(a0d, b2, acc[0][c], 0, 0, 0);
            acc[1][c] = __builtin_amdgcn_mfma_f32_16x16x32_bf16(a1d, b2, acc[1][c], 0, 0, 0);
        }
    }

    // ---- epilogue: BN+ReLU, write bf16 (and stash tile for t3) -------------
    float scv[2], shv[2];
    #pragma unroll
    for (int c = 0; c < 2; c++) {
        int col = (nt0 + c) * 16 + m;
        scv[c] = scale[col]; shv[c] = shift[col];
    }
    #pragma unroll
    for (int mt = 0; mt < 2; mt++) {
        #pragma unroll
        for (int reg = 0; reg < 4; reg++) {
            int rloc = mt * 16 + q * 4 + reg;
            int row  = nb0 + rloc;
            if (row < n) {
                #pragma unroll
                for (int c = 0; c < 2; c++) {
                    int col = (nt0 + c) * 16 + m;
                    float v = fmaxf(acc[mt][c][reg] * scv[c] + shv[c], 0.f);
                    unsigned short u = f2bf(v);
                    out[(size_t)row * 128 + col] = u;
                    if constexpr (T3) sH[rloc * 136 + col] = u;
                }
            }
        }
    }

    // ---- phase 3 (layer 2 only): t3 = hb2_tile @ Wl3, wave = 16 cols -------
    if constexpr (T3) {
        __syncthreads();
        f4v a3c[2];
        #pragma unroll
        for (int mt = 0; mt < 2; mt++) { a3c[mt][0] = 0.f; a3c[mt][1] = 0.f; a3c[mt][2] = 0.f; a3c[mt][3] = 0.f; }
        #pragma unroll
        for (int kt = 0; kt < 4; kt++) {
            const int ko = kt * 32 + q * 8;
            s8v a0 = *(const s8v*)(sH + m * 136 + ko);
            s8v a1 = *(const s8v*)(sH + (16 + m) * 136 + ko);
            s8v b  = *(const s8v*)(W3p + ((size_t)(kt * 4 + wave) * 64 + lane) * 8);
            a3c[0] = __builtin_amdgcn_mfma_f32_16x16x32_bf16(a0, b, a3c[0], 0, 0, 0);
            a3c[1] = __builtin_amdgcn_mfma_f32_16x16x32_bf16(a1, b, a3c[1], 0, 0, 0);
        }
        #pragma unroll
        for (int mt = 0; mt < 2; mt++) {
            #pragma unroll
            for (int reg = 0; reg < 4; reg++) {
                int row = nb0 + mt * 16 + q * 4 + reg;
                if (row < n) t3[(size_t)row * 64 + wave * 16 + m] = f2bf(a3c[mt][reg]);
            }
        }
    }
}

// ---- fused layer 3: gather-mean(t3) + hb2@Wr3 + bias -----------------------
// block = 32 nodes, 4 waves. Gather: eighth-wave per node (8 lanes x uint4),
// 8 nodes concurrent per wave, 1 slot, branch-free unroll-8 rounds.
__global__ __launch_bounds__(256, 8) void k_final(const unsigned short* __restrict__ hb2,
                                               const unsigned short* __restrict__ t3,
                                               const int* __restrict__ cnt, const int* __restrict__ bucket,
                                               const unsigned short* __restrict__ Bp, const float* __restrict__ bias,
                                               float* __restrict__ outf, int n) {
    __shared__ float sG[32 * 68];   // fp32 agg tile, stride 68 floats
    const int tid  = threadIdx.x;
    const int wave = tid >> 6;
    const int lane = tid & 63;
    const int nb0  = blockIdx.x * 32;
    if (nb0 >= n) return;

    // ---- phase 1: gather-mean ----------------------------------------------
    {
        const int e8   = lane >> 3;
        const int li   = lane & 7;
        const int base = e8 << 3;
        const uint4* inp = (const uint4*)t3;       // 128B row = 8 x uint4
        const int row  = wave * 8 + e8;
        const int node = nb0 + row;
        const bool ok  = node < n;
        int c = ok ? cnt[node] : 0; if (c > CAP) c = CAP;
        int idx1 = (ok && li < c)     ? bucket[(size_t)node * CAP + li]     : n;
        int idx2 = (ok && li + 8 < c) ? bucket[(size_t)node * CAP + li + 8] : n;
        f2v a0 = {0.f, 0.f}, a1 = {0.f, 0.f}, a2 = {0.f, 0.f}, a3 = {0.f, 0.f};
        if (c > 0) {
            #pragma unroll
            for (int u = 0; u < 8; u++) {
                int idx = __shfl(idx1, base + u);
                uint4 v = inp[(size_t)idx * 8 + li];
                ACCP(v);
            }
        }
        if (c > 8) {
            #pragma unroll
            for (int u = 0; u < 8; u++) {
                int idx = __shfl(idx2, base + u);
                uint4 v = inp[(size_t)idx * 8 + li];
                ACCP(v);
            }
        }
        for (int s = 16; s < c; s++) {             // deg>16 (rare)
            int idx = bucket[(size_t)node * CAP + s];
            uint4 v = inp[(size_t)idx * 8 + li];
            ACCP(v);
        }
        if (ok) {
            float iv = 1.0f / fmaxf((float)c, 1.0f);
            float4 o1; o1.x = a0[0] * iv; o1.y = a0[1] * iv; o1.z = a1[0] * iv; o1.w = a1[1] * iv;
            float4 o2; o2.x = a2[0] * iv; o2.y = a2[1] * iv; o2.z = a3[0] * iv; o2.w = a3[1] * iv;
            *(float4*)(sG + row * 68 + li * 8)     = o1;
            *(float4*)(sG + row * 68 + li * 8 + 4) = o2;
        }
    }
    __syncthreads();

    // ---- phase 2: out = hb2 @ Wr3 + agg + bias ------------------------------
    const int m = lane & 15;
    const int q = lane >> 4;
    const int rg0 = min(nb0 + m,      n - 1);
    const int rg1 = min(nb0 + 16 + m, n - 1);

    f4v acc[2];
    #pragma unroll
    for (int mt = 0; mt < 2; mt++) { acc[mt][0] = 0.f; acc[mt][1] = 0.f; acc[mt][2] = 0.f; acc[mt][3] = 0.f; }

    #pragma unroll
    for (int kt = 0; kt < 4; kt++) {
        const int ko = kt * 32 + q * 8;
        s8v a0 = *(const s8v*)(hb2 + (size_t)rg0 * 128 + ko);
        s8v a1 = *(const s8v*)(hb2 + (size_t)rg1 * 128 + ko);
        s8v b  = *(const s8v*)(Bp + ((size_t)(kt * 4 + wave) * 64 + lane) * 8);
        acc[0] = __builtin_amdgcn_mfma_f32_16x16x32_bf16(a0, b, acc[0], 0, 0, 0);
        acc[1] = __builtin_amdgcn_mfma_f32_16x16x32_bf16(a1, b, acc[1], 0, 0, 0);
    }

    const int col = wave * 16 + m;
    const float bv = bias[col];
    #pragma unroll
    for (int mt = 0; mt < 2; mt++) {
        #pragma unroll
        for (int reg = 0; reg < 4; reg++) {
            int rloc = mt * 16 + q * 4 + reg;
            int row  = nb0 + rloc;
            if (row < n) outf[(size_t)row * 64 + col] = acc[mt][reg] + sG[rloc * 68 + col] + bv;
        }
    }
}

extern "C" void kernel_launch(void* const* d_in, const int* in_sizes, int n_in,
                              void* d_out, int out_size, void* d_ws, size_t ws_size,
                              hipStream_t stream) {
    const float* x   = (const float*)d_in[0];
    const int*   ei  = (const int*)d_in[1];
    const float* Wl1 = (const float*)d_in[2];
    const float* bl1 = (const float*)d_in[3];
    const float* Wr1 = (const float*)d_in[4];
    const float* g1  = (const float*)d_in[5];
    const float* be1 = (const float*)d_in[6];
    const float* rm1 = (const float*)d_in[7];
    const float* rv1 = (const float*)d_in[8];
    const float* Wl2 = (const float*)d_in[9];
    const float* bl2 = (const float*)d_in[10];
    const float* Wr2 = (const float*)d_in[11];
    const float* g2  = (const float*)d_in[12];
    const float* be2 = (const float*)d_in[13];
    const float* rm2 = (const float*)d_in[14];
    const float* rv2 = (const float*)d_in[15];
    const float* Wl3 = (const float*)d_in[16];
    const float* bl3 = (const float*)d_in[17];
    const float* Wr3 = (const float*)d_in[18];

    const int N = in_sizes[0] / 128;
    const int E = in_sizes[1] / 2;
    const int* src = ei;
    const int* dst = ei + E;

    // workspace layout (feature buffers have N+1 rows; row N is the zero row)
    char* w = (char*)d_ws;
    auto au = [](size_t v) { return (v + 1023) & ~(size_t)1023; };
    size_t off = 0;
    int*            cnt    = (int*)(w + off);            off += au((size_t)N * 4);
    int*            bucket = (int*)(w + off);            off += au((size_t)N * CAP * 4);
    unsigned short* xb     = (unsigned short*)(w + off); off += au((size_t)(N + 1) * 128 * 2);
    unsigned short* hb     = (unsigned short*)(w + off); off += au((size_t)(N + 1) * 128 * 2);
    unsigned short* hb2    = (unsigned short*)(w + off); off += au((size_t)(N + 1) * 128 * 2);
    unsigned short* t3b    = (unsigned short*)(w + off); off += au((size_t)(N + 1) * 64 * 2);
    unsigned short* Wp[6];
    Wp[0] = (unsigned short*)(w + off); off += au(128 * 128 * 2);  // Wl1
    Wp[1] = (unsigned short*)(w + off); off += au(128 * 128 * 2);  // Wr1
    Wp[2] = (unsigned short*)(w + off); off += au(128 * 128 * 2);  // Wl2
    Wp[3] = (unsigned short*)(w + off); off += au(128 * 128 * 2);  // Wr2
    Wp[4] = (unsigned short*)(w + off); off += au(128 * 64 * 2);   // Wl3
    Wp[5] = (unsigned short*)(w + off); off += au(128 * 64 * 2);   // Wr3
    float* P = (float*)(w + off); off += 2048;
    (void)ws_size; (void)n_in;

    hipMemsetAsync(cnt, 0, (size_t)N * 4, stream);

    const int n4 = N * 32;
    const int nbBucket = (E + 255) / 256;
    const int nbCvt    = (n4 + 255) / 256;
    k_prep<<<nbBucket + nbCvt + 448, 256, 0, stream>>>(src, dst, E, cnt, bucket,
                                                       x, xb, n4,
                                                       Wl1, Wr1, Wl2, Wr2, Wl3, Wr3,
                                                       Wp[0], Wp[1], Wp[2], Wp[3], Wp[4], Wp[5],
                                                       g1, be1, rm1, rv1, bl1, g2, be2, rm2, rv2, bl2, P,
                                                       hb, hb2, t3b, N, nbBucket, nbCvt);

    const int grid = (N + 31) / 32;

    // layer 1: hb = relu(bn(agg(x)@Wl1 + bl1 + x@Wr1))
    k_fused<false><<<grid, 256, 0, stream>>>(xb, cnt, bucket, Wp[0], Wp[1],
                                             P, P + 128, hb, nullptr, nullptr, N);
    // layer 2: hb2 = relu(bn(agg(hb)@Wl2 + bl2 + hb@Wr2)); t3b = hb2@Wl3
    k_fused<true><<<grid, 256, 0, stream>>>(hb, cnt, bucket, Wp[2], Wp[3],
                                            P + 256, P + 384, hb2, Wp[4], t3b, N);
    // layer 3: out = agg(t3b) + hb2@Wr3 + bl3
    k_final<<<grid, 256, 0, stream>>>(hb2, t3b, cnt, bucket, Wp[5], bl3, (float*)d_out, N);
}

// Round 8
// 284.605 us; speedup vs baseline: 1.0546x; 1.0546x over previous
//
#include <hip/hip_runtime.h>

#define CAP 48

typedef short  s8v  __attribute__((ext_vector_type(8)));
typedef float  f4v  __attribute__((ext_vector_type(4)));
typedef float  f2v  __attribute__((ext_vector_type(2)));

__device__ __forceinline__ unsigned short f2bf(float f) {
    unsigned u = __float_as_uint(f);
    u += 0x7FFFu + ((u >> 16) & 1u);      // RNE
    return (unsigned short)(u >> 16);
}
__device__ __forceinline__ float bflo(unsigned v) { return __uint_as_float(v << 16); }
__device__ __forceinline__ float bfhi(unsigned v) { return __uint_as_float(v & 0xffff0000u); }

// packed accumulate: 4 x v_pk_add_f32 instead of 8 x v_add_f32 per uint4
#define ACCP(v) do { \
    a0 += (f2v){bflo((v).x), bfhi((v).x)}; \
    a1 += (f2v){bflo((v).y), bfhi((v).y)}; \
    a2 += (f2v){bflo((v).z), bfhi((v).z)}; \
    a3 += (f2v){bflo((v).w), bfhi((v).w)}; } while(0)

// ---- merged prep: bucket CSR + x->bf16 convert + weight pack + BN fold -----
// blocks [0, nbBucket)               : edge bucketing
// blocks [nbBucket, nbBucket+nbCvt)  : fp32 -> bf16 convert of x
// blocks [nbBucket+nbCvt, +448)      : weight prepack (64 x 7 grid linearized)
__global__ __launch_bounds__(256) void k_prep(const int* __restrict__ src, const int* __restrict__ dst, int E,
                                              int* __restrict__ cnt, int* __restrict__ bucket,
                                              const float* __restrict__ x, unsigned short* __restrict__ xb, int n4,
                                              const float* W0, const float* W1, const float* W2,
                                              const float* W3, const float* W4, const float* W5,
                                              unsigned short* P0, unsigned short* P1, unsigned short* P2,
                                              unsigned short* P3, unsigned short* P4, unsigned short* P5,
                                              const float* g1, const float* be1, const float* rm1, const float* rv1, const float* bl1,
                                              const float* g2, const float* be2, const float* rm2, const float* rv2, const float* bl2,
                                              float* P,
                                              unsigned short* hb, unsigned short* hb2, unsigned short* t3b, int N,
                                              int nbBucket, int nbCvt) {
    int b = blockIdx.x;
    const int tid = threadIdx.x;
    if (b < nbBucket) {
        int e = b * 256 + tid;
        if (e < E) {
            int d = dst[e];
            int slot = atomicAdd(&cnt[d], 1);
            if (slot < CAP) bucket[(size_t)d * CAP + slot] = src[e];
        }
        return;
    }
    b -= nbBucket;
    if (b < nbCvt) {
        int i = b * 256 + tid;
        if (i < n4) {
            float4 v = ((const float4*)x)[i];
            ushort4 o;
            o.x = f2bf(v.x); o.y = f2bf(v.y); o.z = f2bf(v.z); o.w = f2bf(v.w);
            ((ushort4*)xb)[i] = o;
        }
        return;
    }
    b -= nbCvt;
    const int px = b & 63;
    const int py = b >> 6;
    if (py == 6) {
        if (px == 0 && tid < 128) {
            int i = tid;
            float s1 = g1[i] * rsqrtf(rv1[i] + 1e-5f);
            P[i]       = s1;
            P[128 + i] = (bl1[i] - rm1[i]) * s1 + be1[i];
            float s2 = g2[i] * rsqrtf(rv2[i] + 1e-5f);
            P[256 + i] = s2;
            P[384 + i] = (bl2[i] - rm2[i]) * s2 + be2[i];
            // zero row N of each feature buffer (gather padding target)
            xb [(size_t)N * 128 + i] = 0;
            hb [(size_t)N * 128 + i] = 0;
            hb2[(size_t)N * 128 + i] = 0;
            if (i < 64) t3b[(size_t)N * 64 + i] = 0;
        }
        return;
    }
    const float* W; unsigned short* Pk; int JD;
    switch (py) {
        case 0: W = W0; Pk = P0; JD = 128; break;
        case 1: W = W1; Pk = P1; JD = 128; break;
        case 2: W = W2; Pk = P2; JD = 128; break;
        case 3: W = W3; Pk = P3; JD = 128; break;
        case 4: W = W4; Pk = P4; JD = 64;  break;
        default:W = W5; Pk = P5; JD = 64;  break;
    }
    int o = px * 256 + tid;
    if (o >= 128 * JD) return;
    int j    = o & 7;
    int lane = (o >> 3) & 63;
    int t    = o >> 9;
    int nt   = t % (JD / 16);
    int kt   = t / (JD / 16);
    int k = kt * 32 + (lane >> 4) * 8 + j;
    int nn = nt * 16 + (lane & 15);
    Pk[o] = f2bf(W[(size_t)k * JD + nn]);
}

// ---- fused SAGE layer: gather-mean -> LDS, dual MFMA, BN+ReLU epilogue -----
// block = 32 nodes, 4 waves. Gather: quarter-wave per node (16 lanes x uint4),
// 2 serial slots/wave, branch-free unroll-8 rounds via zero-row clamping.
// Packed-f32 accumulation (v_pk_add_f32); no occupancy clamp (R7 lesson).
template<bool T3>
__global__ __launch_bounds__(256) void k_fused(const unsigned short* __restrict__ feat,
                                               const int* __restrict__ cnt, const int* __restrict__ bucket,
                                               const unsigned short* __restrict__ Bl, const unsigned short* __restrict__ Br,
                                               const float* __restrict__ scale, const float* __restrict__ shift,
                                               unsigned short* __restrict__ out,
                                               const unsigned short* __restrict__ W3p, unsigned short* __restrict__ t3,
                                               int n) {
    __shared__ unsigned short sA[32 * 136];
    __shared__ unsigned short sH[T3 ? 32 * 136 : 8];
    const int tid  = threadIdx.x;
    const int wave = tid >> 6;
    const int lane = tid & 63;
    const int nb0  = blockIdx.x * 32;
    if (nb0 >= n) return;

    // ---- phase 1: gather-mean ----------------------------------------------
    {
        const int q4   = lane >> 4;
        const int li   = lane & 15;
        const int base = q4 << 4;
        const uint4* inp = (const uint4*)feat;     // 256B row = 16 x uint4
        int rows[2], cs[2], idxs[2];
        #pragma unroll
        for (int t = 0; t < 2; t++) {
            rows[t] = wave * 8 + t * 4 + q4;
            int node = nb0 + rows[t];
            bool ok = node < n;
            int c = ok ? cnt[node] : 0; if (c > CAP) c = CAP;
            cs[t] = c;
            idxs[t] = (ok && li < c) ? bucket[(size_t)node * CAP + li] : n;  // n = zero row
        }
        #pragma unroll
        for (int t = 0; t < 2; t++) {
            const int c = cs[t];
            f2v a0 = {0.f, 0.f}, a1 = {0.f, 0.f}, a2 = {0.f, 0.f}, a3 = {0.f, 0.f};
            if (c > 0) {
                #pragma unroll
                for (int u = 0; u < 8; u++) {
                    int idx = __shfl(idxs[t], base + u);        // >=c lanes hold n (zero row)
                    uint4 v = inp[(size_t)idx * 16 + li];
                    ACCP(v);
                }
            }
            if (c > 8) {
                #pragma unroll
                for (int u = 8; u < 16; u++) {
                    int idx = __shfl(idxs[t], base + u);
                    uint4 v = inp[(size_t)idx * 16 + li];
                    ACCP(v);
                }
            }
            const int node = nb0 + rows[t];
            for (int s = 16; s < c; s++) {                      // deg>16 (rare)
                int idx = bucket[(size_t)node * CAP + s];
                uint4 v = inp[(size_t)idx * 16 + li];
                ACCP(v);
            }
            if (node < n) {
                float iv = 1.0f / fmaxf((float)c, 1.0f);
                uint4 o;
                o.x = (unsigned)f2bf(a0[0] * iv) | ((unsigned)f2bf(a0[1] * iv) << 16);
                o.y = (unsigned)f2bf(a1[0] * iv) | ((unsigned)f2bf(a1[1] * iv) << 16);
                o.z = (unsigned)f2bf(a2[0] * iv) | ((unsigned)f2bf(a2[1] * iv) << 16);
                o.w = (unsigned)f2bf(a3[0] * iv) | ((unsigned)f2bf(a3[1] * iv) << 16);
                *(uint4*)(sA + rows[t] * 136 + li * 8) = o;
            }
        }
    }
    __syncthreads();

    // ---- phase 2: dual MFMA, wave = 32 rows x 32 cols (nt0 = wave*2) --------
    const int m = lane & 15;
    const int q = lane >> 4;
    const int nt0 = wave * 2;
    const int rg0 = min(nb0 + m,      n - 1);
    const int rg1 = min(nb0 + 16 + m, n - 1);

    f4v acc[2][2];
    #pragma unroll
    for (int mt = 0; mt < 2; mt++)
        #pragma unroll
        for (int c = 0; c < 2; c++) {
            acc[mt][c][0] = 0.f; acc[mt][c][1] = 0.f; acc[mt][c][2] = 0.f; acc[mt][c][3] = 0.f;
        }

    #pragma unroll
    for (int kt = 0; kt < 4; kt++) {
        const int ko = kt * 32 + q * 8;
        s8v a0 = *(const s8v*)(sA + m * 136 + ko);                // agg side (LDS)
        s8v a1 = *(const s8v*)(sA + (16 + m) * 136 + ko);
        s8v a0d = *(const s8v*)(feat + (size_t)rg0 * 128 + ko);   // root side (global)
        s8v a1d = *(const s8v*)(feat + (size_t)rg1 * 128 + ko);
        #pragma unroll
        for (int c = 0; c < 2; c++) {
            s8v b  = *(const s8v*)(Bl + ((size_t)(kt * 8 + nt0 + c) * 64 + lane) * 8);
            acc[0][c] = __builtin_amdgcn_mfma_f32_16x16x32_bf16(a0, b, acc[0][c], 0, 0, 0);
            acc[1][c] = __builtin_amdgcn_mfma_f32_16x16x32_bf16(a1, b, acc[1][c], 0, 0, 0);
            s8v b2 = *(const s8v*)(Br + ((size_t)(kt * 8 + nt0 + c) * 64 + lane) * 8);
            acc[0][c] = __builtin_amdgcn_mfma_f32_16x16x32_bf16(a0d, b2, acc[0][c], 0, 0, 0);
            acc[1][c] = __builtin_amdgcn_mfma_f32_16x16x32_bf16(a1d, b2, acc[1][c], 0, 0, 0);
        }
    }

    // ---- epilogue: BN+ReLU, write bf16 (and stash tile for t3) -------------
    float scv[2], shv[2];
    #pragma unroll
    for (int c = 0; c < 2; c++) {
        int col = (nt0 + c) * 16 + m;
        scv[c] = scale[col]; shv[c] = shift[col];
    }
    #pragma unroll
    for (int mt = 0; mt < 2; mt++) {
        #pragma unroll
        for (int reg = 0; reg < 4; reg++) {
            int rloc = mt * 16 + q * 4 + reg;
            int row  = nb0 + rloc;
            if (row < n) {
                #pragma unroll
                for (int c = 0; c < 2; c++) {
                    int col = (nt0 + c) * 16 + m;
                    float v = fmaxf(acc[mt][c][reg] * scv[c] + shv[c], 0.f);
                    unsigned short u = f2bf(v);
                    out[(size_t)row * 128 + col] = u;
                    if constexpr (T3) sH[rloc * 136 + col] = u;
                }
            }
        }
    }

    // ---- phase 3 (layer 2 only): t3 = hb2_tile @ Wl3, wave = 16 cols -------
    if constexpr (T3) {
        __syncthreads();
        f4v a3c[2];
        #pragma unroll
        for (int mt = 0; mt < 2; mt++) { a3c[mt][0] = 0.f; a3c[mt][1] = 0.f; a3c[mt][2] = 0.f; a3c[mt][3] = 0.f; }
        #pragma unroll
        for (int kt = 0; kt < 4; kt++) {
            const int ko = kt * 32 + q * 8;
            s8v a0 = *(const s8v*)(sH + m * 136 + ko);
            s8v a1 = *(const s8v*)(sH + (16 + m) * 136 + ko);
            s8v b  = *(const s8v*)(W3p + ((size_t)(kt * 4 + wave) * 64 + lane) * 8);
            a3c[0] = __builtin_amdgcn_mfma_f32_16x16x32_bf16(a0, b, a3c[0], 0, 0, 0);
            a3c[1] = __builtin_amdgcn_mfma_f32_16x16x32_bf16(a1, b, a3c[1], 0, 0, 0);
        }
        #pragma unroll
        for (int mt = 0; mt < 2; mt++) {
            #pragma unroll
            for (int reg = 0; reg < 4; reg++) {
                int row = nb0 + mt * 16 + q * 4 + reg;
                if (row < n) t3[(size_t)row * 64 + wave * 16 + m] = f2bf(a3c[mt][reg]);
            }
        }
    }
}

// ---- fused layer 3: gather-mean(t3) + hb2@Wr3 + bias -----------------------
// block = 32 nodes, 4 waves. Gather: eighth-wave per node (8 lanes x uint4),
// 8 nodes concurrent per wave, 1 slot, branch-free unroll-8 rounds.
__global__ __launch_bounds__(256) void k_final(const unsigned short* __restrict__ hb2,
                                               const unsigned short* __restrict__ t3,
                                               const int* __restrict__ cnt, const int* __restrict__ bucket,
                                               const unsigned short* __restrict__ Bp, const float* __restrict__ bias,
                                               float* __restrict__ outf, int n) {
    __shared__ float sG[32 * 68];   // fp32 agg tile, stride 68 floats
    const int tid  = threadIdx.x;
    const int wave = tid >> 6;
    const int lane = tid & 63;
    const int nb0  = blockIdx.x * 32;
    if (nb0 >= n) return;

    // ---- phase 1: gather-mean ----------------------------------------------
    {
        const int e8   = lane >> 3;
        const int li   = lane & 7;
        const int base = e8 << 3;
        const uint4* inp = (const uint4*)t3;       // 128B row = 8 x uint4
        const int row  = wave * 8 + e8;
        const int node = nb0 + row;
        const bool ok  = node < n;
        int c = ok ? cnt[node] : 0; if (c > CAP) c = CAP;
        int idx1 = (ok && li < c)     ? bucket[(size_t)node * CAP + li]     : n;
        int idx2 = (ok && li + 8 < c) ? bucket[(size_t)node * CAP + li + 8] : n;
        f2v a0 = {0.f, 0.f}, a1 = {0.f, 0.f}, a2 = {0.f, 0.f}, a3 = {0.f, 0.f};
        if (c > 0) {
            #pragma unroll
            for (int u = 0; u < 8; u++) {
                int idx = __shfl(idx1, base + u);
                uint4 v = inp[(size_t)idx * 8 + li];
                ACCP(v);
            }
        }
        if (c > 8) {
            #pragma unroll
            for (int u = 0; u < 8; u++) {
                int idx = __shfl(idx2, base + u);
                uint4 v = inp[(size_t)idx * 8 + li];
                ACCP(v);
            }
        }
        for (int s = 16; s < c; s++) {             // deg>16 (rare)
            int idx = bucket[(size_t)node * CAP + s];
            uint4 v = inp[(size_t)idx * 8 + li];
            ACCP(v);
        }
        if (ok) {
            float iv = 1.0f / fmaxf((float)c, 1.0f);
            float4 o1; o1.x = a0[0] * iv; o1.y = a0[1] * iv; o1.z = a1[0] * iv; o1.w = a1[1] * iv;
            float4 o2; o2.x = a2[0] * iv; o2.y = a2[1] * iv; o2.z = a3[0] * iv; o2.w = a3[1] * iv;
            *(float4*)(sG + row * 68 + li * 8)     = o1;
            *(float4*)(sG + row * 68 + li * 8 + 4) = o2;
        }
    }
    __syncthreads();

    // ---- phase 2: out = hb2 @ Wr3 + agg + bias ------------------------------
    const int m = lane & 15;
    const int q = lane >> 4;
    const int rg0 = min(nb0 + m,      n - 1);
    const int rg1 = min(nb0 + 16 + m, n - 1);

    f4v acc[2];
    #pragma unroll
    for (int mt = 0; mt < 2; mt++) { acc[mt][0] = 0.f; acc[mt][1] = 0.f; acc[mt][2] = 0.f; acc[mt][3] = 0.f; }

    #pragma unroll
    for (int kt = 0; kt < 4; kt++) {
        const int ko = kt * 32 + q * 8;
        s8v a0 = *(const s8v*)(hb2 + (size_t)rg0 * 128 + ko);
        s8v a1 = *(const s8v*)(hb2 + (size_t)rg1 * 128 + ko);
        s8v b  = *(const s8v*)(Bp + ((size_t)(kt * 4 + wave) * 64 + lane) * 8);
        acc[0] = __builtin_amdgcn_mfma_f32_16x16x32_bf16(a0, b, acc[0], 0, 0, 0);
        acc[1] = __builtin_amdgcn_mfma_f32_16x16x32_bf16(a1, b, acc[1], 0, 0, 0);
    }

    const int col = wave * 16 + m;
    const float bv = bias[col];
    #pragma unroll
    for (int mt = 0; mt < 2; mt++) {
        #pragma unroll
        for (int reg = 0; reg < 4; reg++) {
            int rloc = mt * 16 + q * 4 + reg;
            int row  = nb0 + rloc;
            if (row < n) outf[(size_t)row * 64 + col] = acc[mt][reg] + sG[rloc * 68 + col] + bv;
        }
    }
}

extern "C" void kernel_launch(void* const* d_in, const int* in_sizes, int n_in,
                              void* d_out, int out_size, void* d_ws, size_t ws_size,
                              hipStream_t stream) {
    const float* x   = (const float*)d_in[0];
    const int*   ei  = (const int*)d_in[1];
    const float* Wl1 = (const float*)d_in[2];
    const float* bl1 = (const float*)d_in[3];
    const float* Wr1 = (const float*)d_in[4];
    const float* g1  = (const float*)d_in[5];
    const float* be1 = (const float*)d_in[6];
    const float* rm1 = (const float*)d_in[7];
    const float* rv1 = (const float*)d_in[8];
    const float* Wl2 = (const float*)d_in[9];
    const float* bl2 = (const float*)d_in[10];
    const float* Wr2 = (const float*)d_in[11];
    const float* g2  = (const float*)d_in[12];
    const float* be2 = (const float*)d_in[13];
    const float* rm2 = (const float*)d_in[14];
    const float* rv2 = (const float*)d_in[15];
    const float* Wl3 = (const float*)d_in[16];
    const float* bl3 = (const float*)d_in[17];
    const float* Wr3 = (const float*)d_in[18];

    const int N = in_sizes[0] / 128;
    const int E = in_sizes[1] / 2;
    const int* src = ei;
    const int* dst = ei + E;

    // workspace layout (feature buffers have N+1 rows; row N is the zero row)
    char* w = (char*)d_ws;
    auto au = [](size_t v) { return (v + 1023) & ~(size_t)1023; };
    size_t off = 0;
    int*            cnt    = (int*)(w + off);            off += au((size_t)N * 4);
    int*            bucket = (int*)(w + off);            off += au((size_t)N * CAP * 4);
    unsigned short* xb     = (unsigned short*)(w + off); off += au((size_t)(N + 1) * 128 * 2);
    unsigned short* hb     = (unsigned short*)(w + off); off += au((size_t)(N + 1) * 128 * 2);
    unsigned short* hb2    = (unsigned short*)(w + off); off += au((size_t)(N + 1) * 128 * 2);
    unsigned short* t3b    = (unsigned short*)(w + off); off += au((size_t)(N + 1) * 64 * 2);
    unsigned short* Wp[6];
    Wp[0] = (unsigned short*)(w + off); off += au(128 * 128 * 2);  // Wl1
    Wp[1] = (unsigned short*)(w + off); off += au(128 * 128 * 2);  // Wr1
    Wp[2] = (unsigned short*)(w + off); off += au(128 * 128 * 2);  // Wl2
    Wp[3] = (unsigned short*)(w + off); off += au(128 * 128 * 2);  // Wr2
    Wp[4] = (unsigned short*)(w + off); off += au(128 * 64 * 2);   // Wl3
    Wp[5] = (unsigned short*)(w + off); off += au(128 * 64 * 2);   // Wr3
    float* P = (float*)(w + off); off += 2048;
    (void)ws_size; (void)n_in;

    hipMemsetAsync(cnt, 0, (size_t)N * 4, stream);

    const int n4 = N * 32;
    const int nbBucket = (E + 255) / 256;
    const int nbCvt    = (n4 + 255) / 256;
    k_prep<<<nbBucket + nbCvt + 448, 256, 0, stream>>>(src, dst, E, cnt, bucket,
                                                       x, xb, n4,
                                                       Wl1, Wr1, Wl2, Wr2, Wl3, Wr3,
                                                       Wp[0], Wp[1], Wp[2], Wp[3], Wp[4], Wp[5],
                                                       g1, be1, rm1, rv1, bl1, g2, be2, rm2, rv2, bl2, P,
                                                       hb, hb2, t3b, N, nbBucket, nbCvt);

    const int grid = (N + 31) / 32;

    // layer 1: hb = relu(bn(agg(x)@Wl1 + bl1 + x@Wr1))
    k_fused<false><<<grid, 256, 0, stream>>>(xb, cnt, bucket, Wp[0], Wp[1],
                                             P, P + 128, hb, nullptr, nullptr, N);
    // layer 2: hb2 = relu(bn(agg(hb)@Wl2 + bl2 + hb@Wr2)); t3b = hb2@Wl3
    k_fused<true><<<grid, 256, 0, stream>>>(hb, cnt, bucket, Wp[2], Wp[3],
                                            P + 256, P + 384, hb2, Wp[4], t3b, N);
    // layer 3: out = agg(t3b) + hb2@Wr3 + bl3
    k_final<<<grid, 256, 0, stream>>>(hb2, t3b, cnt, bucket, Wp[5], bl3, (float*)d_out, N);
}

// Round 9
// 282.541 us; speedup vs baseline: 1.0623x; 1.0073x over previous
//
#include <hip/hip_runtime.h>

#define CAP 32

typedef short  s8v  __attribute__((ext_vector_type(8)));
typedef float  f4v  __attribute__((ext_vector_type(4)));
typedef float  f2v  __attribute__((ext_vector_type(2)));

__device__ __forceinline__ unsigned short f2bf(float f) {
    unsigned u = __float_as_uint(f);
    u += 0x7FFFu + ((u >> 16) & 1u);      // RNE
    return (unsigned short)(u >> 16);
}
__device__ __forceinline__ float bflo(unsigned v) { return __uint_as_float(v << 16); }
__device__ __forceinline__ float bfhi(unsigned v) { return __uint_as_float(v & 0xffff0000u); }

// packed accumulate: 4 x v_pk_add_f32 instead of 8 x v_add_f32 per uint4
#define ACCP(v) do { \
    a0 += (f2v){bflo((v).x), bfhi((v).x)}; \
    a1 += (f2v){bflo((v).y), bfhi((v).y)}; \
    a2 += (f2v){bflo((v).z), bfhi((v).z)}; \
    a3 += (f2v){bflo((v).w), bfhi((v).w)}; } while(0)

// ---- merged prep: bucket CSR + x->bf16 convert + weight pack + BN fold -----
// blocks [0, nbBucket)               : edge bucketing
// blocks [nbBucket, nbBucket+nbCvt)  : fp32 -> bf16 convert of x (32B/thread)
// blocks [nbBucket+nbCvt, +448)      : weight prepack (64 x 7 grid linearized)
__global__ __launch_bounds__(256) void k_prep(const int* __restrict__ src, const int* __restrict__ dst, int E,
                                              int* __restrict__ cnt, int* __restrict__ bucket,
                                              const float* __restrict__ x, unsigned short* __restrict__ xb, int n8,
                                              const float* W0, const float* W1, const float* W2,
                                              const float* W3, const float* W4, const float* W5,
                                              unsigned short* P0, unsigned short* P1, unsigned short* P2,
                                              unsigned short* P3, unsigned short* P4, unsigned short* P5,
                                              const float* g1, const float* be1, const float* rm1, const float* rv1, const float* bl1,
                                              const float* g2, const float* be2, const float* rm2, const float* rv2, const float* bl2,
                                              float* P,
                                              unsigned short* hb, unsigned short* hb2, unsigned short* t3b, int N,
                                              int nbBucket, int nbCvt) {
    int b = blockIdx.x;
    const int tid = threadIdx.x;
    if (b < nbBucket) {
        int e = b * 256 + tid;
        if (e < E) {
            int d = dst[e];
            int slot = atomicAdd(&cnt[d], 1);
            if (slot < CAP) bucket[(size_t)d * CAP + slot] = src[e];
        }
        return;
    }
    b -= nbBucket;
    if (b < nbCvt) {
        int i = b * 256 + tid;
        if (i < n8) {
            float4 v0 = ((const float4*)x)[i * 2];
            float4 v1 = ((const float4*)x)[i * 2 + 1];
            ushort4 o0, o1;
            o0.x = f2bf(v0.x); o0.y = f2bf(v0.y); o0.z = f2bf(v0.z); o0.w = f2bf(v0.w);
            o1.x = f2bf(v1.x); o1.y = f2bf(v1.y); o1.z = f2bf(v1.z); o1.w = f2bf(v1.w);
            ((ushort4*)xb)[i * 2]     = o0;
            ((ushort4*)xb)[i * 2 + 1] = o1;
        }
        return;
    }
    b -= nbCvt;
    const int px = b & 63;
    const int py = b >> 6;
    if (py == 6) {
        if (px == 0 && tid < 128) {
            int i = tid;
            float s1 = g1[i] * rsqrtf(rv1[i] + 1e-5f);
            P[i]       = s1;
            P[128 + i] = (bl1[i] - rm1[i]) * s1 + be1[i];
            float s2 = g2[i] * rsqrtf(rv2[i] + 1e-5f);
            P[256 + i] = s2;
            P[384 + i] = (bl2[i] - rm2[i]) * s2 + be2[i];
            // zero row N of each feature buffer (gather padding target)
            xb [(size_t)N * 128 + i] = 0;
            hb [(size_t)N * 128 + i] = 0;
            hb2[(size_t)N * 128 + i] = 0;
            if (i < 64) t3b[(size_t)N * 64 + i] = 0;
        }
        return;
    }
    const float* W; unsigned short* Pk; int JD;
    switch (py) {
        case 0: W = W0; Pk = P0; JD = 128; break;
        case 1: W = W1; Pk = P1; JD = 128; break;
        case 2: W = W2; Pk = P2; JD = 128; break;
        case 3: W = W3; Pk = P3; JD = 128; break;
        case 4: W = W4; Pk = P4; JD = 64;  break;
        default:W = W5; Pk = P5; JD = 64;  break;
    }
    int o = px * 256 + tid;
    if (o >= 128 * JD) return;
    int j    = o & 7;
    int lane = (o >> 3) & 63;
    int t    = o >> 9;
    int nt   = t % (JD / 16);
    int kt   = t / (JD / 16);
    int k = kt * 32 + (lane >> 4) * 8 + j;
    int nn = nt * 16 + (lane & 15);
    Pk[o] = f2bf(W[(size_t)k * JD + nn]);
}

// ---- fused SAGE layer: gather-mean -> LDS, dual MFMA, BN+ReLU epilogue -----
// block = 32 nodes, 4 waves. Gather: quarter-wave per node (16 lanes x uint4),
// 2 serial slots/wave, branch-free unroll-8 rounds via zero-row clamping.
// Packed-f32 accumulation (v_pk_add_f32); no occupancy clamp (R7 lesson).
template<bool T3>
__global__ __launch_bounds__(256) void k_fused(const unsigned short* __restrict__ feat,
                                               const int* __restrict__ cnt, const int* __restrict__ bucket,
                                               const unsigned short* __restrict__ Bl, const unsigned short* __restrict__ Br,
                                               const float* __restrict__ scale, const float* __restrict__ shift,
                                               unsigned short* __restrict__ out,
                                               const unsigned short* __restrict__ W3p, unsigned short* __restrict__ t3,
                                               int n) {
    __shared__ unsigned short sA[32 * 136];
    __shared__ unsigned short sH[T3 ? 32 * 136 : 8];
    const int tid  = threadIdx.x;
    const int wave = tid >> 6;
    const int lane = tid & 63;
    const int nb0  = blockIdx.x * 32;
    if (nb0 >= n) return;

    // ---- phase 1: gather-mean ----------------------------------------------
    {
        const int q4   = lane >> 4;
        const int li   = lane & 15;
        const int base = q4 << 4;
        const uint4* inp = (const uint4*)feat;     // 256B row = 16 x uint4
        int rows[2], cs[2], idxs[2];
        #pragma unroll
        for (int t = 0; t < 2; t++) {
            rows[t] = wave * 8 + t * 4 + q4;
            int node = nb0 + rows[t];
            bool ok = node < n;
            int c = ok ? cnt[node] : 0; if (c > CAP) c = CAP;
            cs[t] = c;
            idxs[t] = (ok && li < c) ? bucket[(size_t)node * CAP + li] : n;  // n = zero row
        }
        #pragma unroll
        for (int t = 0; t < 2; t++) {
            const int c = cs[t];
            f2v a0 = {0.f, 0.f}, a1 = {0.f, 0.f}, a2 = {0.f, 0.f}, a3 = {0.f, 0.f};
            if (c > 0) {
                #pragma unroll
                for (int u = 0; u < 8; u++) {
                    int idx = __shfl(idxs[t], base + u);        // >=c lanes hold n (zero row)
                    uint4 v = inp[(size_t)idx * 16 + li];
                    ACCP(v);
                }
            }
            if (c > 8) {
                #pragma unroll
                for (int u = 8; u < 16; u++) {
                    int idx = __shfl(idxs[t], base + u);
                    uint4 v = inp[(size_t)idx * 16 + li];
                    ACCP(v);
                }
            }
            const int node = nb0 + rows[t];
            for (int s = 16; s < c; s++) {                      // deg>16 (rare)
                int idx = bucket[(size_t)node * CAP + s];
                uint4 v = inp[(size_t)idx * 16 + li];
                ACCP(v);
            }
            if (node < n) {
                float iv = 1.0f / fmaxf((float)c, 1.0f);
                uint4 o;
                o.x = (unsigned)f2bf(a0[0] * iv) | ((unsigned)f2bf(a0[1] * iv) << 16);
                o.y = (unsigned)f2bf(a1[0] * iv) | ((unsigned)f2bf(a1[1] * iv) << 16);
                o.z = (unsigned)f2bf(a2[0] * iv) | ((unsigned)f2bf(a2[1] * iv) << 16);
                o.w = (unsigned)f2bf(a3[0] * iv) | ((unsigned)f2bf(a3[1] * iv) << 16);
                *(uint4*)(sA + rows[t] * 136 + li * 8) = o;
            }
        }
    }
    __syncthreads();

    // ---- phase 2: dual MFMA, wave = 32 rows x 32 cols (nt0 = wave*2) --------
    const int m = lane & 15;
    const int q = lane >> 4;
    const int nt0 = wave * 2;
    const int rg0 = min(nb0 + m,      n - 1);
    const int rg1 = min(nb0 + 16 + m, n - 1);

    f4v acc[2][2];
    #pragma unroll
    for (int mt = 0; mt < 2; mt++)
        #pragma unroll
        for (int c = 0; c < 2; c++) {
            acc[mt][c][0] = 0.f; acc[mt][c][1] = 0.f; acc[mt][c][2] = 0.f; acc[mt][c][3] = 0.f;
        }

    #pragma unroll
    for (int kt = 0; kt < 4; kt++) {
        const int ko = kt * 32 + q * 8;
        s8v a0 = *(const s8v*)(sA + m * 136 + ko);                // agg side (LDS)
        s8v a1 = *(const s8v*)(sA + (16 + m) * 136 + ko);
        s8v a0d = *(const s8v*)(feat + (size_t)rg0 * 128 + ko);   // root side (global)
        s8v a1d = *(const s8v*)(feat + (size_t)rg1 * 128 + ko);
        #pragma unroll
        for (int c = 0; c < 2; c++) {
            s8v b  = *(const s8v*)(Bl + ((size_t)(kt * 8 + nt0 + c) * 64 + lane) * 8);
            acc[0][c] = __builtin_amdgcn_mfma_f32_16x16x32_bf16(a0, b, acc[0][c], 0, 0, 0);
            acc[1][c] = __builtin_amdgcn_mfma_f32_16x16x32_bf16(a1, b, acc[1][c], 0, 0, 0);
            s8v b2 = *(const s8v*)(Br + ((size_t)(kt * 8 + nt0 + c) * 64 + lane) * 8);
            acc[0][c] = __builtin_amdgcn_mfma_f32_16x16x32_bf16(a0d, b2, acc[0][c], 0, 0, 0);
            acc[1][c] = __builtin_amdgcn_mfma_f32_16x16x32_bf16(a1d, b2, acc[1][c], 0, 0, 0);
        }
    }

    // ---- epilogue: BN+ReLU, write bf16 (and stash tile for t3) -------------
    float scv[2], shv[2];
    #pragma unroll
    for (int c = 0; c < 2; c++) {
        int col = (nt0 + c) * 16 + m;
        scv[c] = scale[col]; shv[c] = shift[col];
    }
    #pragma unroll
    for (int mt = 0; mt < 2; mt++) {
        #pragma unroll
        for (int reg = 0; reg < 4; reg++) {
            int rloc = mt * 16 + q * 4 + reg;
            int row  = nb0 + rloc;
            if (row < n) {
                #pragma unroll
                for (int c = 0; c < 2; c++) {
                    int col = (nt0 + c) * 16 + m;
                    float v = fmaxf(acc[mt][c][reg] * scv[c] + shv[c], 0.f);
                    unsigned short u = f2bf(v);
                    out[(size_t)row * 128 + col] = u;
                    if constexpr (T3) sH[rloc * 136 + col] = u;
                }
            }
        }
    }

    // ---- phase 3 (layer 2 only): t3 = hb2_tile @ Wl3, wave = 16 cols -------
    if constexpr (T3) {
        __syncthreads();
        f4v a3c[2];
        #pragma unroll
        for (int mt = 0; mt < 2; mt++) { a3c[mt][0] = 0.f; a3c[mt][1] = 0.f; a3c[mt][2] = 0.f; a3c[mt][3] = 0.f; }
        #pragma unroll
        for (int kt = 0; kt < 4; kt++) {
            const int ko = kt * 32 + q * 8;
            s8v a0 = *(const s8v*)(sH + m * 136 + ko);
            s8v a1 = *(const s8v*)(sH + (16 + m) * 136 + ko);
            s8v b  = *(const s8v*)(W3p + ((size_t)(kt * 4 + wave) * 64 + lane) * 8);
            a3c[0] = __builtin_amdgcn_mfma_f32_16x16x32_bf16(a0, b, a3c[0], 0, 0, 0);
            a3c[1] = __builtin_amdgcn_mfma_f32_16x16x32_bf16(a1, b, a3c[1], 0, 0, 0);
        }
        #pragma unroll
        for (int mt = 0; mt < 2; mt++) {
            #pragma unroll
            for (int reg = 0; reg < 4; reg++) {
                int row = nb0 + mt * 16 + q * 4 + reg;
                if (row < n) t3[(size_t)row * 64 + wave * 16 + m] = f2bf(a3c[mt][reg]);
            }
        }
    }
}

// ---- fused layer 3: gather-mean(t3) + hb2@Wr3 + bias -----------------------
// block = 32 nodes, 4 waves. Gather: eighth-wave per node (8 lanes x uint4),
// 8 nodes concurrent per wave, 1 slot, branch-free unroll-8 rounds.
__global__ __launch_bounds__(256) void k_final(const unsigned short* __restrict__ hb2,
                                               const unsigned short* __restrict__ t3,
                                               const int* __restrict__ cnt, const int* __restrict__ bucket,
                                               const unsigned short* __restrict__ Bp, const float* __restrict__ bias,
                                               float* __restrict__ outf, int n) {
    __shared__ float sG[32 * 68];   // fp32 agg tile, stride 68 floats
    const int tid  = threadIdx.x;
    const int wave = tid >> 6;
    const int lane = tid & 63;
    const int nb0  = blockIdx.x * 32;
    if (nb0 >= n) return;

    // ---- phase 1: gather-mean ----------------------------------------------
    {
        const int e8   = lane >> 3;
        const int li   = lane & 7;
        const int base = e8 << 3;
        const uint4* inp = (const uint4*)t3;       // 128B row = 8 x uint4
        const int row  = wave * 8 + e8;
        const int node = nb0 + row;
        const bool ok  = node < n;
        int c = ok ? cnt[node] : 0; if (c > CAP) c = CAP;
        int idx1 = (ok && li < c)     ? bucket[(size_t)node * CAP + li]     : n;
        int idx2 = (ok && li + 8 < c) ? bucket[(size_t)node * CAP + li + 8] : n;
        f2v a0 = {0.f, 0.f}, a1 = {0.f, 0.f}, a2 = {0.f, 0.f}, a3 = {0.f, 0.f};
        if (c > 0) {
            #pragma unroll
            for (int u = 0; u < 8; u++) {
                int idx = __shfl(idx1, base + u);
                uint4 v = inp[(size_t)idx * 8 + li];
                ACCP(v);
            }
        }
        if (c > 8) {
            #pragma unroll
            for (int u = 0; u < 8; u++) {
                int idx = __shfl(idx2, base + u);
                uint4 v = inp[(size_t)idx * 8 + li];
                ACCP(v);
            }
        }
        for (int s = 16; s < c; s++) {             // deg>16 (rare)
            int idx = bucket[(size_t)node * CAP + s];
            uint4 v = inp[(size_t)idx * 8 + li];
            ACCP(v);
        }
        if (ok) {
            float iv = 1.0f / fmaxf((float)c, 1.0f);
            float4 o1; o1.x = a0[0] * iv; o1.y = a0[1] * iv; o1.z = a1[0] * iv; o1.w = a1[1] * iv;
            float4 o2; o2.x = a2[0] * iv; o2.y = a2[1] * iv; o2.z = a3[0] * iv; o2.w = a3[1] * iv;
            *(float4*)(sG + row * 68 + li * 8)     = o1;
            *(float4*)(sG + row * 68 + li * 8 + 4) = o2;
        }
    }
    __syncthreads();

    // ---- phase 2: out = hb2 @ Wr3 + agg + bias ------------------------------
    const int m = lane & 15;
    const int q = lane >> 4;
    const int rg0 = min(nb0 + m,      n - 1);
    const int rg1 = min(nb0 + 16 + m, n - 1);

    f4v acc[2];
    #pragma unroll
    for (int mt = 0; mt < 2; mt++) { acc[mt][0] = 0.f; acc[mt][1] = 0.f; acc[mt][2] = 0.f; acc[mt][3] = 0.f; }

    #pragma unroll
    for (int kt = 0; kt < 4; kt++) {
        const int ko = kt * 32 + q * 8;
        s8v a0 = *(const s8v*)(hb2 + (size_t)rg0 * 128 + ko);
        s8v a1 = *(const s8v*)(hb2 + (size_t)rg1 * 128 + ko);
        s8v b  = *(const s8v*)(Bp + ((size_t)(kt * 4 + wave) * 64 + lane) * 8);
        acc[0] = __builtin_amdgcn_mfma_f32_16x16x32_bf16(a0, b, acc[0], 0, 0, 0);
        acc[1] = __builtin_amdgcn_mfma_f32_16x16x32_bf16(a1, b, acc[1], 0, 0, 0);
    }

    const int col = wave * 16 + m;
    const float bv = bias[col];
    #pragma unroll
    for (int mt = 0; mt < 2; mt++) {
        #pragma unroll
        for (int reg = 0; reg < 4; reg++) {
            int rloc = mt * 16 + q * 4 + reg;
            int row  = nb0 + rloc;
            if (row < n) outf[(size_t)row * 64 + col] = acc[mt][reg] + sG[rloc * 68 + col] + bv;
        }
    }
}

extern "C" void kernel_launch(void* const* d_in, const int* in_sizes, int n_in,
                              void* d_out, int out_size, void* d_ws, size_t ws_size,
                              hipStream_t stream) {
    const float* x   = (const float*)d_in[0];
    const int*   ei  = (const int*)d_in[1];
    const float* Wl1 = (const float*)d_in[2];
    const float* bl1 = (const float*)d_in[3];
    const float* Wr1 = (const float*)d_in[4];
    const float* g1  = (const float*)d_in[5];
    const float* be1 = (const float*)d_in[6];
    const float* rm1 = (const float*)d_in[7];
    const float* rv1 = (const float*)d_in[8];
    const float* Wl2 = (const float*)d_in[9];
    const float* bl2 = (const float*)d_in[10];
    const float* Wr2 = (const float*)d_in[11];
    const float* g2  = (const float*)d_in[12];
    const float* be2 = (const float*)d_in[13];
    const float* rm2 = (const float*)d_in[14];
    const float* rv2 = (const float*)d_in[15];
    const float* Wl3 = (const float*)d_in[16];
    const float* bl3 = (const float*)d_in[17];
    const float* Wr3 = (const float*)d_in[18];

    const int N = in_sizes[0] / 128;
    const int E = in_sizes[1] / 2;
    const int* src = ei;
    const int* dst = ei + E;

    // workspace layout (feature buffers have N+1 rows; row N is the zero row)
    char* w = (char*)d_ws;
    auto au = [](size_t v) { return (v + 1023) & ~(size_t)1023; };
    size_t off = 0;
    int*            cnt    = (int*)(w + off);            off += au((size_t)N * 4);
    int*            bucket = (int*)(w + off);            off += au((size_t)N * CAP * 4);
    unsigned short* xb     = (unsigned short*)(w + off); off += au((size_t)(N + 1) * 128 * 2);
    unsigned short* hb     = (unsigned short*)(w + off); off += au((size_t)(N + 1) * 128 * 2);
    unsigned short* hb2    = (unsigned short*)(w + off); off += au((size_t)(N + 1) * 128 * 2);
    unsigned short* t3b    = (unsigned short*)(w + off); off += au((size_t)(N + 1) * 64 * 2);
    unsigned short* Wp[6];
    Wp[0] = (unsigned short*)(w + off); off += au(128 * 128 * 2);  // Wl1
    Wp[1] = (unsigned short*)(w + off); off += au(128 * 128 * 2);  // Wr1
    Wp[2] = (unsigned short*)(w + off); off += au(128 * 128 * 2);  // Wl2
    Wp[3] = (unsigned short*)(w + off); off += au(128 * 128 * 2);  // Wr2
    Wp[4] = (unsigned short*)(w + off); off += au(128 * 64 * 2);   // Wl3
    Wp[5] = (unsigned short*)(w + off); off += au(128 * 64 * 2);   // Wr3
    float* P = (float*)(w + off); off += 2048;
    (void)ws_size; (void)n_in;

    hipMemsetAsync(cnt, 0, (size_t)N * 4, stream);

    const int n8 = N * 16;                         // N*128/8
    const int nbBucket = (E + 255) / 256;
    const int nbCvt    = (n8 + 255) / 256;
    k_prep<<<nbBucket + nbCvt + 448, 256, 0, stream>>>(src, dst, E, cnt, bucket,
                                                       x, xb, n8,
                                                       Wl1, Wr1, Wl2, Wr2, Wl3, Wr3,
                                                       Wp[0], Wp[1], Wp[2], Wp[3], Wp[4], Wp[5],
                                                       g1, be1, rm1, rv1, bl1, g2, be2, rm2, rv2, bl2, P,
                                                       hb, hb2, t3b, N, nbBucket, nbCvt);

    const int grid = (N + 31) / 32;

    // layer 1: hb = relu(bn(agg(x)@Wl1 + bl1 + x@Wr1))
    k_fused<false><<<grid, 256, 0, stream>>>(xb, cnt, bucket, Wp[0], Wp[1],
                                             P, P + 128, hb, nullptr, nullptr, N);
    // layer 2: hb2 = relu(bn(agg(hb)@Wl2 + bl2 + hb@Wr2)); t3b = hb2@Wl3
    k_fused<true><<<grid, 256, 0, stream>>>(hb, cnt, bucket, Wp[2], Wp[3],
                                            P + 256, P + 384, hb2, Wp[4], t3b, N);
    // layer 3: out = agg(t3b) + hb2@Wr3 + bl3
    k_final<<<grid, 256, 0, stream>>>(hb2, t3b, cnt, bucket, Wp[5], bl3, (float*)d_out, N);
}